// Round 3
// baseline (755.533 us; speedup 1.0000x reference)
//
#include <hip/hip_runtime.h>

// Problem constants (B=8, N=2048, H=2048, E=4, I=2048)
#define HDIM 2048
#define IDIM 2048
#define KD   2048
#define ME   4096   // tokens per expert (B*N/E)
#define NT   64     // K tiles of 32

// Workspace layout (requires >= 234,881,024 bytes):
//   xb    @ 0         : bf16 x regrouped [e][t][h], 64 MiB
//   w1t   @ 64 MiB    : bf16 gate_up^T  [e][d][h], 64 MiB
//   w2t   @ 128 MiB   : bf16 down^T     [e][h][i], 32 MiB
//   inter @ 160 MiB   : bf16 silu(g)*u  [e][t][i], 64 MiB

typedef __bf16 bf16x8 __attribute__((ext_vector_type(8)));
typedef float f32x4 __attribute__((ext_vector_type(4)));

__device__ __forceinline__ unsigned short f2bf(float f) {
  unsigned u = __builtin_bit_cast(unsigned, f);
  u += 0x7FFFu + ((u >> 16) & 1u);   // round-to-nearest-even
  return (unsigned short)(u >> 16);
}

__device__ __forceinline__ void gld16(const void* g, void* l) {
  __builtin_amdgcn_global_load_lds(
      (const __attribute__((address_space(1))) unsigned int*)g,
      (__attribute__((address_space(3))) unsigned int*)l, 16, 0, 0);
}

template<int N> __device__ __forceinline__ void wait_vmcnt() {
  asm volatile("s_waitcnt vmcnt(%0)" :: "i"(N) : "memory");
}

// ---- Kernel 1: convert x fp32 -> bf16, regroup rows per expert ----
__global__ void __launch_bounds__(256) pack_x(const float* __restrict__ x,
                                              unsigned short* __restrict__ xb) {
  const int row = blockIdx.x;            // 0..16383 = b*2048 + n
  const int n = row & 2047;
  const int b = row >> 11;
  const int e = n & 3, g = n >> 2;
  const float4* src = (const float4*)(x + (size_t)row * HDIM);
  unsigned short* dst = xb + ((size_t)e * ME + b * 512 + g) * HDIM;
  const int t = threadIdx.x;
  float4 v0 = src[2 * t];
  float4 v1 = src[2 * t + 1];
  uint4 pk;
  pk.x = (unsigned)f2bf(v0.x) | ((unsigned)f2bf(v0.y) << 16);
  pk.y = (unsigned)f2bf(v0.z) | ((unsigned)f2bf(v0.w) << 16);
  pk.z = (unsigned)f2bf(v1.x) | ((unsigned)f2bf(v1.y) << 16);
  pk.w = (unsigned)f2bf(v1.z) | ((unsigned)f2bf(v1.w) << 16);
  *(uint4*)(dst + 8 * t) = pk;
}

// ---- Kernel 2: transpose + cast fp32 (R x C) -> bf16 (C x R), per expert z ----
__global__ void __launch_bounds__(256) transpose_cvt(const float* __restrict__ src,
                                                     unsigned short* __restrict__ dst,
                                                     int R, int C) {
  __shared__ unsigned short tile[32][33];
  const size_t eo = (size_t)blockIdx.z * R * C;
  src += eo;
  dst += eo;
  const int c0 = blockIdx.x * 32, r0 = blockIdx.y * 32;
  const int tx = threadIdx.x & 31, ty = threadIdx.x >> 5;
#pragma unroll
  for (int j = 0; j < 4; ++j) {
    int r = r0 + ty + j * 8;
    tile[ty + j * 8][tx] = f2bf(src[(size_t)r * C + c0 + tx]);
  }
  __syncthreads();
#pragma unroll
  for (int j = 0; j < 4; ++j) {
    int c = c0 + ty + j * 8;
    dst[(size_t)c * R + r0 + tx] = tile[tx][ty + j * 8];
  }
}

// ==== Counted-vmcnt 4-slot pipeline GEMMs, phase-interleaved reads ====
// LDS: 4 slots x 32 KiB (A[256x32] @ +0, B[256x32] @ +16 KiB), st_16x32 swizzle.
// Tile t in slot t&3; body t stages tile t+3. Per tile: 1x vmcnt(4) + 1x barrier.
// vmcnt(4) at body t certifies stage(t+1) landed (leaves stage(t+2) in flight),
// so NEXT-tile boundary fragments (a01', B') may be ds_read inside body t after
// the barrier -> LDS reads flow continuously under the MFMA stream instead of
// bursting at tile top (this was the 48%-MfmaUtil alternation stall).
// Body: [frag reads already in regs] vmcnt(4); barrier; stage 4x gld16;
//   P0 {read a23 | 8 MFMA a01}; P1 {read a45 | 8 MFMA a23};
//   P2 {read a67 | 8 MFMA a45}; P3 {read next a01,B into TEMPS | 8 MFMA a67 with
//   CURRENT B; commit temps after}.  <-- R2 bug: B was overwritten before use.
// Tail: VMN 4,0,0 over last 3 bodies; prologue vmcnt(8)+barrier before 1st reads.

template<int BASE>
__device__ __forceinline__ void g1_mfma8(const bf16x8* ap, const bf16x8 (&bg)[2],
                                         const bf16x8 (&bu)[2],
                                         f32x4 (&accg)[8][2], f32x4 (&accu)[8][2]) {
#pragma unroll
  for (int k = 0; k < 2; ++k)
#pragma unroll
    for (int j = 0; j < 2; ++j) {
      accg[BASE + k][j] = __builtin_amdgcn_mfma_f32_16x16x32_bf16(ap[k], bg[j], accg[BASE + k][j], 0, 0, 0);
      accu[BASE + k][j] = __builtin_amdgcn_mfma_f32_16x16x32_bf16(ap[k], bu[j], accu[BASE + k][j], 0, 0, 0);
    }
}

template<int VMN, bool STG, bool PRE>
__device__ __forceinline__ void g1_body(const unsigned short* Scur, const unsigned short* Snxt,
                                        int ab0, int bb0,
                                        const unsigned short*& ap0, const unsigned short*& ap1,
                                        const unsigned short*& bgp, const unsigned short*& bup,
                                        unsigned short* sb,
                                        bf16x8 (&a01)[2], bf16x8 (&bg)[2], bf16x8 (&bu)[2],
                                        f32x4 (&accg)[8][2], f32x4 (&accu)[8][2]) {
  wait_vmcnt<VMN>();
  __builtin_amdgcn_s_barrier();
  asm volatile("" ::: "memory");
  if constexpr (STG) {
    gld16(ap0, sb); gld16(ap1, sb + 4096); gld16(bgp, sb + 8192); gld16(bup, sb + 12288);
    ap0 += 32; ap1 += 32; bgp += 32; bup += 32;
  }
  bf16x8 a23[2], a45[2], a67[2];
  // P0: read a23 | mfma a01
  a23[0] = *(const bf16x8*)(Scur + ab0 + 2 * 512);
  a23[1] = *(const bf16x8*)(Scur + ab0 + 3 * 512);
  __builtin_amdgcn_s_setprio(1);
  g1_mfma8<0>(a01, bg, bu, accg, accu);
  __builtin_amdgcn_s_setprio(0);
  // P1: read a45 | mfma a23
  a45[0] = *(const bf16x8*)(Scur + ab0 + 4 * 512);
  a45[1] = *(const bf16x8*)(Scur + ab0 + 5 * 512);
  __builtin_amdgcn_s_setprio(1);
  g1_mfma8<2>(a23, bg, bu, accg, accu);
  __builtin_amdgcn_s_setprio(0);
  // P2: read a67 | mfma a45
  a67[0] = *(const bf16x8*)(Scur + ab0 + 6 * 512);
  a67[1] = *(const bf16x8*)(Scur + ab0 + 7 * 512);
  __builtin_amdgcn_s_setprio(1);
  g1_mfma8<4>(a45, bg, bu, accg, accu);
  __builtin_amdgcn_s_setprio(0);
  // P3: read next-tile boundary frags into temps | mfma a67 with CURRENT bg/bu
  bf16x8 bgn[2], bun[2];
  if constexpr (PRE) {
    a01[0] = *(const bf16x8*)(Snxt + ab0);            // a01 not used by a67 MFMA
    a01[1] = *(const bf16x8*)(Snxt + ab0 + 512);
    bgn[0] = *(const bf16x8*)(Snxt + bb0);
    bgn[1] = *(const bf16x8*)(Snxt + bb0 + 512);
    bun[0] = *(const bf16x8*)(Snxt + bb0 + 4096);
    bun[1] = *(const bf16x8*)(Snxt + bb0 + 4096 + 512);
  }
  __builtin_amdgcn_s_setprio(1);
  g1_mfma8<6>(a67, bg, bu, accg, accu);
  __builtin_amdgcn_s_setprio(0);
  if constexpr (PRE) {
    bg[0] = bgn[0]; bg[1] = bgn[1];
    bu[0] = bun[0]; bu[1] = bun[1];
  }
}

// ---- Kernel 3: GEMM1 + fused SiLU-gate. Block 256 M x 128 i-cols, 8 waves. ----
__global__ void __launch_bounds__(512) gemm1_silu(const unsigned short* __restrict__ xb,
                                                  const unsigned short* __restrict__ w1t,
                                                  unsigned short* __restrict__ inter) {
  __shared__ unsigned short SM[65536];   // 128 KiB: 4 slots x (A 8192 | B 8192) elems
  const int e = blockIdx.z;
  const int m0 = blockIdx.x * 256;
  const int c0 = blockIdx.y * 128;       // i-tile
  const int t = threadIdx.x;
  const int lane = t & 63;
  const int wave = t >> 6;
  const int wm = wave >> 2;              // 0..1 : 128-row half
  const int wn = wave & 3;               // 0..3 : 32-col quarter

  const unsigned short* xe = xb + (size_t)e * ME * KD;
  const unsigned short* we = w1t + (size_t)e * 4096 * KD;

  const int srow = t >> 2;
  const int scol = ((t & 3) * 8) ^ ((t & 32) ? 16 : 0);   // inverse-swizzled source
  const unsigned short* ap0 = xe + (size_t)(m0 + srow) * KD + scol;
  const unsigned short* ap1 = ap0 + (size_t)128 * KD;
  const unsigned short* bgp = we + (size_t)(c0 + srow) * KD + scol;
  const unsigned short* bup = bgp + (size_t)2048 * KD;

  const int l15 = lane & 15;
  const int kqs = ((lane >> 4) * 8) ^ ((lane & 8) ? 16 : 0);
  const int ab0 = (wm * 128 + l15) * 32 + kqs;
  const int bb0 = 8192 + (wn * 32 + l15) * 32 + kqs;   // gate rows; up = +4096

  f32x4 accg[8][2] = {};
  f32x4 accu[8][2] = {};

  // prologue: stage tiles 0..2 (12 loads), certify stage(0), read tile-0 boundary frags
#pragma unroll
  for (int s = 0; s < 3; ++s) {
    unsigned short* sb = SM + s * 16384 + t * 8;
    gld16(ap0, sb); gld16(ap1, sb + 4096); gld16(bgp, sb + 8192); gld16(bup, sb + 12288);
    ap0 += 32; ap1 += 32; bgp += 32; bup += 32;
  }
  wait_vmcnt<8>();
  __builtin_amdgcn_s_barrier();
  asm volatile("" ::: "memory");
  bf16x8 a01[2], bg[2], bu[2];
  a01[0] = *(const bf16x8*)(SM + ab0);
  a01[1] = *(const bf16x8*)(SM + ab0 + 512);
  bg[0] = *(const bf16x8*)(SM + bb0);
  bg[1] = *(const bf16x8*)(SM + bb0 + 512);
  bu[0] = *(const bf16x8*)(SM + bb0 + 4096);
  bu[1] = *(const bf16x8*)(SM + bb0 + 4096 + 512);

#pragma unroll 1
  for (int kt = 0; kt < NT - 3; ++kt)    // bodies 0..NT-4, each stages tile kt+3
    g1_body<4, true, true>(SM + (kt & 3) * 16384, SM + ((kt + 1) & 3) * 16384, ab0, bb0,
                           ap0, ap1, bgp, bup, SM + ((kt + 3) & 3) * 16384 + t * 8,
                           a01, bg, bu, accg, accu);
  g1_body<4, false, true>(SM + ((NT - 3) & 3) * 16384, SM + ((NT - 2) & 3) * 16384, ab0, bb0,
                          ap0, ap1, bgp, bup, SM, a01, bg, bu, accg, accu);
  g1_body<0, false, true>(SM + ((NT - 2) & 3) * 16384, SM + ((NT - 1) & 3) * 16384, ab0, bb0,
                          ap0, ap1, bgp, bup, SM, a01, bg, bu, accg, accu);
  g1_body<0, false, false>(SM + ((NT - 1) & 3) * 16384, SM, ab0, bb0,
                           ap0, ap1, bgp, bup, SM, a01, bg, bu, accg, accu);

  // Epilogue: silu(g)*u -> bf16 out-tile in LDS (stride 136), coalesced stores.
  // Out-tile uses SM[0..34816) elems — disjoint from slot 3 (>=49152) still read.
  const int quad = lane >> 4;
#pragma unroll
  for (int i = 0; i < 8; ++i)
#pragma unroll
    for (int j = 0; j < 2; ++j)
#pragma unroll
      for (int r = 0; r < 4; ++r) {
        int row = wm * 128 + i * 16 + quad * 4 + r;
        int col = wn * 32 + j * 16 + l15;
        float g = accg[i][j][r];
        float u = accu[i][j][r];
        float sv = g / (1.0f + __expf(-g));
        SM[row * 136 + col] = f2bf(sv * u);
      }
  __syncthreads();
  unsigned short* ip = inter + ((size_t)e * ME + m0) * IDIM + c0;
#pragma unroll
  for (int p = 0; p < 8; ++p) {
    int idx = p * 512 + t;               // 4096 uint4s: 256 rows x 16 parts
    int row = idx >> 4, part = idx & 15;
    *(uint4*)(ip + (size_t)row * IDIM + part * 8) = *(const uint4*)(SM + row * 136 + part * 8);
  }
}

template<int BASE>
__device__ __forceinline__ void g2_mfma8(const bf16x8* ap, const bf16x8 (&b)[4],
                                         f32x4 (&acc)[8][4]) {
#pragma unroll
  for (int k = 0; k < 2; ++k)
#pragma unroll
    for (int j = 0; j < 4; ++j)
      acc[BASE + k][j] = __builtin_amdgcn_mfma_f32_16x16x32_bf16(ap[k], b[j], acc[BASE + k][j], 0, 0, 0);
}

template<int VMN, bool STG, bool PRE>
__device__ __forceinline__ void g2_body(const unsigned short* Scur, const unsigned short* Snxt,
                                        int ab0, int bb0,
                                        const unsigned short*& ap0, const unsigned short*& ap1,
                                        const unsigned short*& bp0, const unsigned short*& bp1,
                                        unsigned short* sb,
                                        bf16x8 (&a01)[2], bf16x8 (&b)[4], f32x4 (&acc)[8][4]) {
  wait_vmcnt<VMN>();
  __builtin_amdgcn_s_barrier();
  asm volatile("" ::: "memory");
  if constexpr (STG) {
    gld16(ap0, sb); gld16(ap1, sb + 4096); gld16(bp0, sb + 8192); gld16(bp1, sb + 12288);
    ap0 += 32; ap1 += 32; bp0 += 32; bp1 += 32;
  }
  bf16x8 a23[2], a45[2], a67[2];
  a23[0] = *(const bf16x8*)(Scur + ab0 + 2 * 512);
  a23[1] = *(const bf16x8*)(Scur + ab0 + 3 * 512);
  __builtin_amdgcn_s_setprio(1);
  g2_mfma8<0>(a01, b, acc);
  __builtin_amdgcn_s_setprio(0);
  a45[0] = *(const bf16x8*)(Scur + ab0 + 4 * 512);
  a45[1] = *(const bf16x8*)(Scur + ab0 + 5 * 512);
  __builtin_amdgcn_s_setprio(1);
  g2_mfma8<2>(a23, b, acc);
  __builtin_amdgcn_s_setprio(0);
  a67[0] = *(const bf16x8*)(Scur + ab0 + 6 * 512);
  a67[1] = *(const bf16x8*)(Scur + ab0 + 7 * 512);
  __builtin_amdgcn_s_setprio(1);
  g2_mfma8<4>(a45, b, acc);
  __builtin_amdgcn_s_setprio(0);
  // P3: next-tile frags into temps; a67 MFMA uses CURRENT b; commit after.
  bf16x8 bn[4];
  if constexpr (PRE) {
    a01[0] = *(const bf16x8*)(Snxt + ab0);
    a01[1] = *(const bf16x8*)(Snxt + ab0 + 512);
#pragma unroll
    for (int j = 0; j < 4; ++j) bn[j] = *(const bf16x8*)(Snxt + bb0 + j * 512);
  }
  __builtin_amdgcn_s_setprio(1);
  g2_mfma8<6>(a67, b, acc);
  __builtin_amdgcn_s_setprio(0);
  if constexpr (PRE) {
#pragma unroll
    for (int j = 0; j < 4; ++j) b[j] = bn[j];
  }
}

// ---- Kernel 4: GEMM2, 256x256 block, scattered fp32 output rows ----
__global__ void __launch_bounds__(512) gemm2(const unsigned short* __restrict__ inter,
                                             const unsigned short* __restrict__ w2t,
                                             float* __restrict__ out) {
  __shared__ unsigned short SM[65536];
  const int e = blockIdx.z;
  const int m0 = blockIdx.x * 256;
  const int n0 = blockIdx.y * 256;
  const int t = threadIdx.x;
  const int lane = t & 63;
  const int wave = t >> 6;
  const int wm = wave >> 2;              // 0..1
  const int wn = wave & 3;               // 0..3 : 64-col quarter

  const unsigned short* ae = inter + (size_t)e * ME * IDIM;
  const unsigned short* be = w2t + (size_t)e * HDIM * IDIM;

  const int srow = t >> 2;
  const int scol = ((t & 3) * 8) ^ ((t & 32) ? 16 : 0);
  const unsigned short* ap0 = ae + (size_t)(m0 + srow) * IDIM + scol;
  const unsigned short* ap1 = ap0 + (size_t)128 * IDIM;
  const unsigned short* bp0 = be + (size_t)(n0 + srow) * IDIM + scol;
  const unsigned short* bp1 = bp0 + (size_t)128 * IDIM;

  const int l15 = lane & 15;
  const int kqs = ((lane >> 4) * 8) ^ ((lane & 8) ? 16 : 0);
  const int ab0 = (wm * 128 + l15) * 32 + kqs;
  const int bb0 = 8192 + (wn * 64 + l15) * 32 + kqs;

  f32x4 acc[8][4] = {};

#pragma unroll
  for (int s = 0; s < 3; ++s) {
    unsigned short* sb = SM + s * 16384 + t * 8;
    gld16(ap0, sb); gld16(ap1, sb + 4096); gld16(bp0, sb + 8192); gld16(bp1, sb + 12288);
    ap0 += 32; ap1 += 32; bp0 += 32; bp1 += 32;
  }
  wait_vmcnt<8>();
  __builtin_amdgcn_s_barrier();
  asm volatile("" ::: "memory");
  bf16x8 a01[2], b[4];
  a01[0] = *(const bf16x8*)(SM + ab0);
  a01[1] = *(const bf16x8*)(SM + ab0 + 512);
#pragma unroll
  for (int j = 0; j < 4; ++j) b[j] = *(const bf16x8*)(SM + bb0 + j * 512);

#pragma unroll 1
  for (int kt = 0; kt < NT - 3; ++kt)
    g2_body<4, true, true>(SM + (kt & 3) * 16384, SM + ((kt + 1) & 3) * 16384, ab0, bb0,
                           ap0, ap1, bp0, bp1, SM + ((kt + 3) & 3) * 16384 + t * 8,
                           a01, b, acc);
  g2_body<4, false, true>(SM + ((NT - 3) & 3) * 16384, SM + ((NT - 2) & 3) * 16384, ab0, bb0,
                          ap0, ap1, bp0, bp1, SM, a01, b, acc);
  g2_body<0, false, true>(SM + ((NT - 2) & 3) * 16384, SM + ((NT - 1) & 3) * 16384, ab0, bb0,
                          ap0, ap1, bp0, bp1, SM, a01, b, acc);
  g2_body<0, false, false>(SM + ((NT - 1) & 3) * 16384, SM, ab0, bb0,
                           ap0, ap1, bp0, bp1, SM, a01, b, acc);

  // scatter rows: expert-grouped row t -> out row b*2048 + g*4 + e
  const int quad = lane >> 4;
#pragma unroll
  for (int i = 0; i < 8; ++i)
#pragma unroll
    for (int r = 0; r < 4; ++r) {
      int trow = m0 + wm * 128 + i * 16 + quad * 4 + r;
      int b_ = trow >> 9, g_ = trow & 511;
      float* orow = out + ((size_t)((b_ << 11) + (g_ << 2) + e)) * HDIM + n0 + wn * 64;
#pragma unroll
      for (int j = 0; j < 4; ++j) orow[j * 16 + l15] = acc[i][j][r];
    }
}

extern "C" void kernel_launch(void* const* d_in, const int* in_sizes, int n_in,
                              void* d_out, int out_size, void* d_ws, size_t ws_size,
                              hipStream_t stream) {
  (void)in_sizes; (void)n_in; (void)out_size; (void)ws_size;
  const float* x  = (const float*)d_in[0];
  const float* w1 = (const float*)d_in[1];
  const float* w2 = (const float*)d_in[2];
  float* out = (float*)d_out;

  char* ws = (char*)d_ws;
  unsigned short* xb    = (unsigned short*)(ws);
  unsigned short* w1t   = (unsigned short*)(ws + 67108864);
  unsigned short* w2t   = (unsigned short*)(ws + 134217728);
  unsigned short* inter = (unsigned short*)(ws + 167772160);

  pack_x<<<16384, 256, 0, stream>>>(x, xb);
  transpose_cvt<<<dim3(128, 64, 4), 256, 0, stream>>>(w1, w1t, 2048, 4096);
  transpose_cvt<<<dim3(64, 64, 4), 256, 0, stream>>>(w2, w2t, 2048, 2048);
  gemm1_silu<<<dim3(16, 16, 4), 512, 0, stream>>>(xb, w1t, inter);
  gemm2<<<dim3(16, 8, 4), 512, 0, stream>>>(inter, w2t, out);
}

// Round 4
// 749.130 us; speedup vs baseline: 1.0085x; 1.0085x over previous
//
#include <hip/hip_runtime.h>

// Problem constants (B=8, N=2048, H=2048, E=4, I=2048)
#define HDIM 2048
#define IDIM 2048
#define KD   2048
#define ME   4096   // tokens per expert (B*N/E)
#define NT2  32     // K tiles of 64

// Workspace layout (requires >= 234,881,024 bytes):
//   xb    @ 0         : bf16 x regrouped [e][t][h], 64 MiB
//   w1t   @ 64 MiB    : bf16 gate_up^T  [e][d][h], 64 MiB
//   w2t   @ 128 MiB   : bf16 down^T     [e][h][i], 32 MiB
//   inter @ 160 MiB   : bf16 silu(g)*u  [e][t][i], 64 MiB

typedef __bf16 bf16x8 __attribute__((ext_vector_type(8)));
typedef float f32x4 __attribute__((ext_vector_type(4)));

__device__ __forceinline__ unsigned short f2bf(float f) {
  unsigned u = __builtin_bit_cast(unsigned, f);
  u += 0x7FFFu + ((u >> 16) & 1u);   // round-to-nearest-even
  return (unsigned short)(u >> 16);
}

__device__ __forceinline__ void gld16(const void* g, void* l) {
  __builtin_amdgcn_global_load_lds(
      (const __attribute__((address_space(1))) unsigned int*)g,
      (__attribute__((address_space(3))) unsigned int*)l, 16, 0, 0);
}

template<int N> __device__ __forceinline__ void wait_vmcnt() {
  asm volatile("s_waitcnt vmcnt(%0)" :: "i"(N) : "memory");
}

// m201-style phase sync: barrier, wait own ds_reads, pin MFMAs below (rule #18).
__device__ __forceinline__ void midbar() {
  __builtin_amdgcn_s_barrier();
  asm volatile("s_waitcnt lgkmcnt(0)" ::: "memory");
  __builtin_amdgcn_sched_barrier(0);
}
__device__ __forceinline__ void endbar() {
  __builtin_amdgcn_s_barrier();
  asm volatile("" ::: "memory");
}

// ---- Kernel 1: convert x fp32 -> bf16, regroup rows per expert ----
__global__ void __launch_bounds__(256) pack_x(const float* __restrict__ x,
                                              unsigned short* __restrict__ xb) {
  const int row = blockIdx.x;            // 0..16383 = b*2048 + n
  const int n = row & 2047;
  const int b = row >> 11;
  const int e = n & 3, g = n >> 2;
  const float4* src = (const float4*)(x + (size_t)row * HDIM);
  unsigned short* dst = xb + ((size_t)e * ME + b * 512 + g) * HDIM;
  const int t = threadIdx.x;
  float4 v0 = src[2 * t];
  float4 v1 = src[2 * t + 1];
  uint4 pk;
  pk.x = (unsigned)f2bf(v0.x) | ((unsigned)f2bf(v0.y) << 16);
  pk.y = (unsigned)f2bf(v0.z) | ((unsigned)f2bf(v0.w) << 16);
  pk.z = (unsigned)f2bf(v1.x) | ((unsigned)f2bf(v1.y) << 16);
  pk.w = (unsigned)f2bf(v1.z) | ((unsigned)f2bf(v1.w) << 16);
  *(uint4*)(dst + 8 * t) = pk;
}

// ---- Kernel 2: transpose + cast fp32 (R x C) -> bf16 (C x R), per expert z ----
__global__ void __launch_bounds__(256) transpose_cvt(const float* __restrict__ src,
                                                     unsigned short* __restrict__ dst,
                                                     int R, int C) {
  __shared__ unsigned short tile[32][33];
  const size_t eo = (size_t)blockIdx.z * R * C;
  src += eo;
  dst += eo;
  const int c0 = blockIdx.x * 32, r0 = blockIdx.y * 32;
  const int tx = threadIdx.x & 31, ty = threadIdx.x >> 5;
#pragma unroll
  for (int j = 0; j < 4; ++j) {
    int r = r0 + ty + j * 8;
    tile[ty + j * 8][tx] = f2bf(src[(size_t)r * C + c0 + tx]);
  }
  __syncthreads();
#pragma unroll
  for (int j = 0; j < 4; ++j) {
    int c = c0 + ty + j * 8;
    dst[(size_t)c * R + r0 + tx] = tile[tx][ty + j * 8];
  }
}

// ==== m201-template GEMMs: BK=64, 2 slots, 4 double-barrier phases/K-tile ====
// LDS slot (64 KiB, elements): c0 = A k0-31 [256r][32k] @0 ; c1 = B k0-31 @8192 ;
//   c2 = A k32-63 @16384 ; c3 = B k32-63 @24576. st_16x32 swizzle within rows
//   (linear gld16 dest, inverse-swizzled global source, swizzled ds_read).
// Staging: tile kt's phases issue tile kt+1's chunks, one per phase (c0..c3),
//   2 gld16 each. vmcnt ledger (8 loads max in flight):
//   prologue: issue t0 c0..c3, vmcnt(4) -> t0 c0,c1 landed.
//   phase2: after issuing next c1, vmcnt(4) retires cur c2,c3 (for phase3 reads).
//   phase4: after issuing next c3, vmcnt(4) retires next c0,c1 (for next phase1).
//   Last tile: no stage, vmcnt(0) at phase2; certification always = vmcnt+barrier
//   one full phase before the dependent ds_reads.
// Phase: {ds_read subtile; issue stage chunk; [vmcnt]; barrier; lgkmcnt(0);
//   setprio(1); 16 MFMA; setprio(0); barrier}  — real barriers pace the 8 waves
//   so each phase's LDS burst overlaps the neighbor phases' MFMA (m196/m201).

// ---- Kernel 3 K64 body: GEMM1 (A 256xK; B = gate rows 0-127, up 128-255) ----
template<bool STG, int VM2, int VM4>
__device__ __forceinline__ void g1_k64(const unsigned short* S, unsigned short* sb,
                                       int ab0, int bb0,
                                       const unsigned short* ap0, const unsigned short* ap1,
                                       const unsigned short* bgp, const unsigned short* bup,
                                       f32x4 (&accg)[8][2], f32x4 (&accu)[8][2]) {
  bf16x8 a[4], bg[2], bu[2];
  // phase 1: k0, m-frags 0-3 (+ B k0)
#pragma unroll
  for (int i = 0; i < 4; ++i) a[i] = *(const bf16x8*)(S + ab0 + i * 512);
  bg[0] = *(const bf16x8*)(S + 8192 + bb0);
  bg[1] = *(const bf16x8*)(S + 8192 + bb0 + 512);
  bu[0] = *(const bf16x8*)(S + 8192 + bb0 + 4096);
  bu[1] = *(const bf16x8*)(S + 8192 + bb0 + 4096 + 512);
  if constexpr (STG) { gld16(ap0, sb); gld16(ap1, sb + 4096); }          // next c0
  midbar();
  __builtin_amdgcn_s_setprio(1);
#pragma unroll
  for (int i = 0; i < 4; ++i)
#pragma unroll
    for (int j = 0; j < 2; ++j) {
      accg[i][j] = __builtin_amdgcn_mfma_f32_16x16x32_bf16(a[i], bg[j], accg[i][j], 0, 0, 0);
      accu[i][j] = __builtin_amdgcn_mfma_f32_16x16x32_bf16(a[i], bu[j], accu[i][j], 0, 0, 0);
    }
  __builtin_amdgcn_s_setprio(0);
  endbar();
  // phase 2: k0, m-frags 4-7
#pragma unroll
  for (int i = 0; i < 4; ++i) a[i] = *(const bf16x8*)(S + ab0 + (i + 4) * 512);
  if constexpr (STG) { gld16(bgp, sb + 8192); gld16(bup, sb + 12288); }  // next c1
  wait_vmcnt<VM2>();                                                     // cur c2,c3 landed
  midbar();
  __builtin_amdgcn_s_setprio(1);
#pragma unroll
  for (int i = 0; i < 4; ++i)
#pragma unroll
    for (int j = 0; j < 2; ++j) {
      accg[i + 4][j] = __builtin_amdgcn_mfma_f32_16x16x32_bf16(a[i], bg[j], accg[i + 4][j], 0, 0, 0);
      accu[i + 4][j] = __builtin_amdgcn_mfma_f32_16x16x32_bf16(a[i], bu[j], accu[i + 4][j], 0, 0, 0);
    }
  __builtin_amdgcn_s_setprio(0);
  endbar();
  // phase 3: k1, m-frags 0-3 (+ B k1)
#pragma unroll
  for (int i = 0; i < 4; ++i) a[i] = *(const bf16x8*)(S + 16384 + ab0 + i * 512);
  bg[0] = *(const bf16x8*)(S + 24576 + bb0);
  bg[1] = *(const bf16x8*)(S + 24576 + bb0 + 512);
  bu[0] = *(const bf16x8*)(S + 24576 + bb0 + 4096);
  bu[1] = *(const bf16x8*)(S + 24576 + bb0 + 4096 + 512);
  if constexpr (STG) { gld16(ap0 + 32, sb + 16384); gld16(ap1 + 32, sb + 20480); } // next c2
  midbar();
  __builtin_amdgcn_s_setprio(1);
#pragma unroll
  for (int i = 0; i < 4; ++i)
#pragma unroll
    for (int j = 0; j < 2; ++j) {
      accg[i][j] = __builtin_amdgcn_mfma_f32_16x16x32_bf16(a[i], bg[j], accg[i][j], 0, 0, 0);
      accu[i][j] = __builtin_amdgcn_mfma_f32_16x16x32_bf16(a[i], bu[j], accu[i][j], 0, 0, 0);
    }
  __builtin_amdgcn_s_setprio(0);
  endbar();
  // phase 4: k1, m-frags 4-7
#pragma unroll
  for (int i = 0; i < 4; ++i) a[i] = *(const bf16x8*)(S + 16384 + ab0 + (i + 4) * 512);
  if constexpr (STG) { gld16(bgp + 32, sb + 24576); gld16(bup + 32, sb + 28672); } // next c3
  wait_vmcnt<VM4>();                                                     // next c0,c1 landed
  midbar();
  __builtin_amdgcn_s_setprio(1);
#pragma unroll
  for (int i = 0; i < 4; ++i)
#pragma unroll
    for (int j = 0; j < 2; ++j) {
      accg[i + 4][j] = __builtin_amdgcn_mfma_f32_16x16x32_bf16(a[i], bg[j], accg[i + 4][j], 0, 0, 0);
      accu[i + 4][j] = __builtin_amdgcn_mfma_f32_16x16x32_bf16(a[i], bu[j], accu[i + 4][j], 0, 0, 0);
    }
  __builtin_amdgcn_s_setprio(0);
  endbar();
}

// ---- Kernel 3: GEMM1 + fused SiLU-gate. Block 256 M x 128 i-cols, 8 waves. ----
__global__ void __launch_bounds__(512) gemm1_silu(const unsigned short* __restrict__ xb,
                                                  const unsigned short* __restrict__ w1t,
                                                  unsigned short* __restrict__ inter) {
  __shared__ unsigned short SM[65536];   // 128 KiB: 2 slots x 64 KiB
  const int e = blockIdx.z;
  const int m0 = blockIdx.x * 256;
  const int c0 = blockIdx.y * 128;       // i-tile
  const int t = threadIdx.x;
  const int lane = t & 63;
  const int wave = t >> 6;
  const int wm = wave >> 2;              // 0..1 : 128-row half
  const int wn = wave & 3;               // 0..3 : 32-col quarter

  const unsigned short* xe = xb + (size_t)e * ME * KD;
  const unsigned short* we = w1t + (size_t)e * 4096 * KD;

  const int srow = t >> 2;
  const int scol = ((t & 3) * 8) ^ ((t & 32) ? 16 : 0);   // inverse-swizzled source
  const unsigned short* ap0 = xe + (size_t)(m0 + srow) * KD + scol;   // A rows 0-127
  const unsigned short* ap1 = ap0 + (size_t)128 * KD;                 // A rows 128-255
  const unsigned short* bgp = we + (size_t)(c0 + srow) * KD + scol;   // gate rows
  const unsigned short* bup = bgp + (size_t)2048 * KD;                // up rows

  const int l15 = lane & 15;
  const int kqs = ((lane >> 4) * 8) ^ ((lane & 8) ? 16 : 0);
  const int ab0 = (wm * 128 + l15) * 32 + kqs;
  const int bb0 = (wn * 32 + l15) * 32 + kqs;   // within B chunk; up = +4096

  f32x4 accg[8][2] = {};
  f32x4 accu[8][2] = {};

  // prologue: stage tile0 chunks c0..c3 in ledger order, certify c0,c1
  {
    unsigned short* sb = SM + t * 8;
    gld16(ap0, sb);        gld16(ap1, sb + 4096);
    gld16(bgp, sb + 8192); gld16(bup, sb + 12288);
    gld16(ap0 + 32, sb + 16384); gld16(ap1 + 32, sb + 20480);
    gld16(bgp + 32, sb + 24576); gld16(bup + 32, sb + 28672);
  }
  wait_vmcnt<4>();
  __builtin_amdgcn_s_barrier();
  asm volatile("" ::: "memory");

#pragma unroll 1
  for (int kt = 0; kt < NT2 - 1; ++kt) {
    ap0 += 64; ap1 += 64; bgp += 64; bup += 64;   // -> tile kt+1
    g1_k64<true, 4, 4>(SM + (kt & 1) * 32768, SM + ((kt + 1) & 1) * 32768 + t * 8,
                       ab0, bb0, ap0, ap1, bgp, bup, accg, accu);
  }
  g1_k64<false, 0, 0>(SM + ((NT2 - 1) & 1) * 32768, SM, ab0, bb0,
                      ap0, ap1, bgp, bup, accg, accu);

  // Epilogue: silu(g)*u -> bf16 out-tile in LDS (stride 136), coalesced stores.
  const int quad = lane >> 4;
#pragma unroll
  for (int i = 0; i < 8; ++i)
#pragma unroll
    for (int j = 0; j < 2; ++j)
#pragma unroll
      for (int r = 0; r < 4; ++r) {
        int row = wm * 128 + i * 16 + quad * 4 + r;
        int col = wn * 32 + j * 16 + l15;
        float g = accg[i][j][r];
        float u = accu[i][j][r];
        float sv = g / (1.0f + __expf(-g));
        SM[row * 136 + col] = f2bf(sv * u);
      }
  __syncthreads();
  unsigned short* ip = inter + ((size_t)e * ME + m0) * IDIM + c0;
#pragma unroll
  for (int p = 0; p < 8; ++p) {
    int idx = p * 512 + t;               // 4096 uint4s: 256 rows x 16 parts
    int row = idx >> 4, part = idx & 15;
    *(uint4*)(ip + (size_t)row * IDIM + part * 8) = *(const uint4*)(SM + row * 136 + part * 8);
  }
}

// ---- Kernel 4 K64 body: GEMM2 (256x256 tile) ----
template<bool STG, int VM2, int VM4>
__device__ __forceinline__ void g2_k64(const unsigned short* S, unsigned short* sb,
                                       int ab0, int bb0,
                                       const unsigned short* ap0, const unsigned short* ap1,
                                       const unsigned short* bp0, const unsigned short* bp1,
                                       f32x4 (&acc)[8][4]) {
  bf16x8 a[4], b[4];
  // phase 1: k0, m0-3 (+ B k0)
#pragma unroll
  for (int i = 0; i < 4; ++i) a[i] = *(const bf16x8*)(S + ab0 + i * 512);
#pragma unroll
  for (int j = 0; j < 4; ++j) b[j] = *(const bf16x8*)(S + 8192 + bb0 + j * 512);
  if constexpr (STG) { gld16(ap0, sb); gld16(ap1, sb + 4096); }
  midbar();
  __builtin_amdgcn_s_setprio(1);
#pragma unroll
  for (int i = 0; i < 4; ++i)
#pragma unroll
    for (int j = 0; j < 4; ++j)
      acc[i][j] = __builtin_amdgcn_mfma_f32_16x16x32_bf16(a[i], b[j], acc[i][j], 0, 0, 0);
  __builtin_amdgcn_s_setprio(0);
  endbar();
  // phase 2: k0, m4-7
#pragma unroll
  for (int i = 0; i < 4; ++i) a[i] = *(const bf16x8*)(S + ab0 + (i + 4) * 512);
  if constexpr (STG) { gld16(bp0, sb + 8192); gld16(bp1, sb + 12288); }
  wait_vmcnt<VM2>();
  midbar();
  __builtin_amdgcn_s_setprio(1);
#pragma unroll
  for (int i = 0; i < 4; ++i)
#pragma unroll
    for (int j = 0; j < 4; ++j)
      acc[i + 4][j] = __builtin_amdgcn_mfma_f32_16x16x32_bf16(a[i], b[j], acc[i + 4][j], 0, 0, 0);
  __builtin_amdgcn_s_setprio(0);
  endbar();
  // phase 3: k1, m0-3 (+ B k1)
#pragma unroll
  for (int i = 0; i < 4; ++i) a[i] = *(const bf16x8*)(S + 16384 + ab0 + i * 512);
#pragma unroll
  for (int j = 0; j < 4; ++j) b[j] = *(const bf16x8*)(S + 24576 + bb0 + j * 512);
  if constexpr (STG) { gld16(ap0 + 32, sb + 16384); gld16(ap1 + 32, sb + 20480); }
  midbar();
  __builtin_amdgcn_s_setprio(1);
#pragma unroll
  for (int i = 0; i < 4; ++i)
#pragma unroll
    for (int j = 0; j < 4; ++j)
      acc[i][j] = __builtin_amdgcn_mfma_f32_16x16x32_bf16(a[i], b[j], acc[i][j], 0, 0, 0);
  __builtin_amdgcn_s_setprio(0);
  endbar();
  // phase 4: k1, m4-7
#pragma unroll
  for (int i = 0; i < 4; ++i) a[i] = *(const bf16x8*)(S + 16384 + ab0 + (i + 4) * 512);
  if constexpr (STG) { gld16(bp0 + 32, sb + 24576); gld16(bp1 + 32, sb + 28672); }
  wait_vmcnt<VM4>();
  midbar();
  __builtin_amdgcn_s_setprio(1);
#pragma unroll
  for (int i = 0; i < 4; ++i)
#pragma unroll
    for (int j = 0; j < 4; ++j)
      acc[i + 4][j] = __builtin_amdgcn_mfma_f32_16x16x32_bf16(a[i], b[j], acc[i + 4][j], 0, 0, 0);
  __builtin_amdgcn_s_setprio(0);
  endbar();
}

// ---- Kernel 4: GEMM2, 256x256 block, scattered fp32 output rows ----
__global__ void __launch_bounds__(512) gemm2(const unsigned short* __restrict__ inter,
                                             const unsigned short* __restrict__ w2t,
                                             float* __restrict__ out) {
  __shared__ unsigned short SM[65536];
  const int e = blockIdx.z;
  const int m0 = blockIdx.x * 256;
  const int n0 = blockIdx.y * 256;
  const int t = threadIdx.x;
  const int lane = t & 63;
  const int wave = t >> 6;
  const int wm = wave >> 2;              // 0..1
  const int wn = wave & 3;               // 0..3 : 64-col quarter

  const unsigned short* ae = inter + (size_t)e * ME * IDIM;
  const unsigned short* be = w2t + (size_t)e * HDIM * IDIM;

  const int srow = t >> 2;
  const int scol = ((t & 3) * 8) ^ ((t & 32) ? 16 : 0);
  const unsigned short* ap0 = ae + (size_t)(m0 + srow) * IDIM + scol;
  const unsigned short* ap1 = ap0 + (size_t)128 * IDIM;
  const unsigned short* bp0 = be + (size_t)(n0 + srow) * IDIM + scol;
  const unsigned short* bp1 = bp0 + (size_t)128 * IDIM;

  const int l15 = lane & 15;
  const int kqs = ((lane >> 4) * 8) ^ ((lane & 8) ? 16 : 0);
  const int ab0 = (wm * 128 + l15) * 32 + kqs;
  const int bb0 = (wn * 64 + l15) * 32 + kqs;

  f32x4 acc[8][4] = {};

  {
    unsigned short* sb = SM + t * 8;
    gld16(ap0, sb);        gld16(ap1, sb + 4096);
    gld16(bp0, sb + 8192); gld16(bp1, sb + 12288);
    gld16(ap0 + 32, sb + 16384); gld16(ap1 + 32, sb + 20480);
    gld16(bp0 + 32, sb + 24576); gld16(bp1 + 32, sb + 28672);
  }
  wait_vmcnt<4>();
  __builtin_amdgcn_s_barrier();
  asm volatile("" ::: "memory");

#pragma unroll 1
  for (int kt = 0; kt < NT2 - 1; ++kt) {
    ap0 += 64; ap1 += 64; bp0 += 64; bp1 += 64;
    g2_k64<true, 4, 4>(SM + (kt & 1) * 32768, SM + ((kt + 1) & 1) * 32768 + t * 8,
                       ab0, bb0, ap0, ap1, bp0, bp1, acc);
  }
  g2_k64<false, 0, 0>(SM + ((NT2 - 1) & 1) * 32768, SM, ab0, bb0,
                      ap0, ap1, bp0, bp1, acc);

  // scatter rows: expert-grouped row t -> out row b*2048 + g*4 + e
  const int quad = lane >> 4;
#pragma unroll
  for (int i = 0; i < 8; ++i)
#pragma unroll
    for (int r = 0; r < 4; ++r) {
      int trow = m0 + wm * 128 + i * 16 + quad * 4 + r;
      int b_ = trow >> 9, g_ = trow & 511;
      float* orow = out + ((size_t)((b_ << 11) + (g_ << 2) + e)) * HDIM + n0 + wn * 64;
#pragma unroll
      for (int j = 0; j < 4; ++j) orow[j * 16 + l15] = acc[i][j][r];
    }
}

extern "C" void kernel_launch(void* const* d_in, const int* in_sizes, int n_in,
                              void* d_out, int out_size, void* d_ws, size_t ws_size,
                              hipStream_t stream) {
  (void)in_sizes; (void)n_in; (void)out_size; (void)ws_size;
  const float* x  = (const float*)d_in[0];
  const float* w1 = (const float*)d_in[1];
  const float* w2 = (const float*)d_in[2];
  float* out = (float*)d_out;

  char* ws = (char*)d_ws;
  unsigned short* xb    = (unsigned short*)(ws);
  unsigned short* w1t   = (unsigned short*)(ws + 67108864);
  unsigned short* w2t   = (unsigned short*)(ws + 134217728);
  unsigned short* inter = (unsigned short*)(ws + 167772160);

  pack_x<<<16384, 256, 0, stream>>>(x, xb);
  transpose_cvt<<<dim3(128, 64, 4), 256, 0, stream>>>(w1, w1t, 2048, 4096);
  transpose_cvt<<<dim3(64, 64, 4), 256, 0, stream>>>(w2, w2t, 2048, 2048);
  gemm1_silu<<<dim3(16, 16, 4), 512, 0, stream>>>(xb, w1t, inter);
  gemm2<<<dim3(16, 8, 4), 512, 0, stream>>>(inter, w2t, out);
}

// Round 5
// 718.856 us; speedup vs baseline: 1.0510x; 1.0421x over previous
//
#include <hip/hip_runtime.h>

// Problem constants (B=8, N=2048, H=2048, E=4, I=2048)
#define HDIM 2048
#define IDIM 2048
#define KD   2048
#define ME   4096   // tokens per expert (B*N/E)
#define NT   64     // K tiles of 32

// Workspace layout (requires >= 234,881,024 bytes):
//   xb    @ 0         : bf16 x regrouped [e][t][h], 64 MiB
//   w1t   @ 64 MiB    : bf16 gate_up^T  [e][d][h], 64 MiB
//   w2t   @ 128 MiB   : bf16 down^T     [e][h][i], 32 MiB
//   inter @ 160 MiB   : bf16 silu(g)*u  [e][t][i], 64 MiB

typedef __bf16 bf16x8 __attribute__((ext_vector_type(8)));
typedef float f32x4 __attribute__((ext_vector_type(4)));

__device__ __forceinline__ unsigned short f2bf(float f) {
  unsigned u = __builtin_bit_cast(unsigned, f);
  u += 0x7FFFu + ((u >> 16) & 1u);   // round-to-nearest-even
  return (unsigned short)(u >> 16);
}

__device__ __forceinline__ void gld16(const void* g, void* l) {
  __builtin_amdgcn_global_load_lds(
      (const __attribute__((address_space(1))) unsigned int*)g,
      (__attribute__((address_space(3))) unsigned int*)l, 16, 0, 0);
}

template<int N> __device__ __forceinline__ void wait_vmcnt() {
  asm volatile("s_waitcnt vmcnt(%0)" :: "i"(N) : "memory");
}

// ---- Kernel 1: convert x fp32 -> bf16, regroup rows per expert ----
__global__ void __launch_bounds__(256) pack_x(const float* __restrict__ x,
                                              unsigned short* __restrict__ xb) {
  const int row = blockIdx.x;            // 0..16383 = b*2048 + n
  const int n = row & 2047;
  const int b = row >> 11;
  const int e = n & 3, g = n >> 2;
  const float4* src = (const float4*)(x + (size_t)row * HDIM);
  unsigned short* dst = xb + ((size_t)e * ME + b * 512 + g) * HDIM;
  const int t = threadIdx.x;
  float4 v0 = src[2 * t];
  float4 v1 = src[2 * t + 1];
  uint4 pk;
  pk.x = (unsigned)f2bf(v0.x) | ((unsigned)f2bf(v0.y) << 16);
  pk.y = (unsigned)f2bf(v0.z) | ((unsigned)f2bf(v0.w) << 16);
  pk.z = (unsigned)f2bf(v1.x) | ((unsigned)f2bf(v1.y) << 16);
  pk.w = (unsigned)f2bf(v1.z) | ((unsigned)f2bf(v1.w) << 16);
  *(uint4*)(dst + 8 * t) = pk;
}

// ---- Kernel 2 (v2): transpose + cast fp32 (R x C) -> bf16 (C x R), per expert z ----
// 32 (rows) x 128 (cols) tile per 256-thread block. Vectorized both sides:
//   loads  float4 (16 B/lane, coalesced 512 B per 32-lane row-group)
//   stores uint4  (16 B/lane, 64 B contiguous per 4-lane group)
// LDS natural layout [32][132] u16 (pad 4 -> 8B-aligned b64 writes, spread banks).
__global__ void __launch_bounds__(256) transpose_cvt(const float* __restrict__ src,
                                                     unsigned short* __restrict__ dst,
                                                     int R, int C) {
  __shared__ unsigned short T[32 * 132];
  const size_t eo = (size_t)blockIdx.z * R * C;
  src += eo;
  dst += eo;
  const int c0 = blockIdx.x * 128, r0 = blockIdx.y * 32;
  const int t = threadIdx.x;
#pragma unroll
  for (int p = 0; p < 4; ++p) {
    int idx = p * 256 + t;
    int rr = idx >> 5;          // 0..31
    int c4 = idx & 31;          // float4 index within row
    float4 v = *(const float4*)(src + (size_t)(r0 + rr) * C + c0 + c4 * 4);
    uint2 pk;
    pk.x = (unsigned)f2bf(v.x) | ((unsigned)f2bf(v.y) << 16);
    pk.y = (unsigned)f2bf(v.z) | ((unsigned)f2bf(v.w) << 16);
    *(uint2*)(T + rr * 132 + c4 * 4) = pk;   // byte off 264*rr + 8*c4, 8B-aligned
  }
  __syncthreads();
#pragma unroll
  for (int q = 0; q < 2; ++q) {
    int idx = q * 256 + t;
    int cc = idx >> 2;          // 0..127 : output row (source col)
    int part = idx & 3;         // 8-elem chunk within 32 outputs
    unsigned short s0 = T[(part * 8 + 0) * 132 + cc];
    unsigned short s1 = T[(part * 8 + 1) * 132 + cc];
    unsigned short s2 = T[(part * 8 + 2) * 132 + cc];
    unsigned short s3 = T[(part * 8 + 3) * 132 + cc];
    unsigned short s4 = T[(part * 8 + 4) * 132 + cc];
    unsigned short s5 = T[(part * 8 + 5) * 132 + cc];
    unsigned short s6 = T[(part * 8 + 6) * 132 + cc];
    unsigned short s7 = T[(part * 8 + 7) * 132 + cc];
    uint4 w;
    w.x = (unsigned)s0 | ((unsigned)s1 << 16);
    w.y = (unsigned)s2 | ((unsigned)s3 << 16);
    w.z = (unsigned)s4 | ((unsigned)s5 << 16);
    w.w = (unsigned)s6 | ((unsigned)s7 << 16);
    *(uint4*)(dst + (size_t)(c0 + cc) * R + r0 + part * 8) = w;
  }
}

// ==== Counted-vmcnt 4-slot pipeline GEMMs (R1 structure, best measured) ====
// LDS: 4 slots x 32 KiB (A[256x32] @ +0, B[256x32] @ +16 KiB), st_16x32 swizzle:
//   element (row, c) lives at byte row*64 + (c ^ ((row&8)?16:0))*2  (linear gld16
//   dest, inverse-swizzled GLOBAL source, swizzled ds_read addr — m201/m173).
// Tile t in slot t&3. Tile t's body stages tile t+3 (slot of t-1: fully read,
// certified by tile t's top barrier). One s_waitcnt vmcnt(8) + one s_barrier per
// tile; vmcnt drains 8->4->0 over the last 3 tiles. 4 gld16/thread/tile.

// ---- Kernel 3 tile body: GEMM1 (A 256xK, gate 128 + up 128 cols per block) ----
template<int VMN, bool STG>
__device__ __forceinline__ void g1_tile(const unsigned short* S, int ab0, int bb0,
                                        const unsigned short*& ap0, const unsigned short*& ap1,
                                        const unsigned short*& bgp, const unsigned short*& bup,
                                        unsigned short* sb,
                                        f32x4 (&accg)[8][2], f32x4 (&accu)[8][2]) {
  wait_vmcnt<VMN>();                 // my stage-loads for this tile landed
  __builtin_amdgcn_s_barrier();      // everyone's landed; prev-tile reads done
  asm volatile("" ::: "memory");
  bf16x8 a[4], bg[2], bu[2];
#pragma unroll
  for (int i = 0; i < 4; ++i) a[i] = *(const bf16x8*)(S + ab0 + i * 512);
#pragma unroll
  for (int j = 0; j < 2; ++j) {
    bg[j] = *(const bf16x8*)(S + bb0 + j * 512);
    bu[j] = *(const bf16x8*)(S + bb0 + 4096 + j * 512);
  }
  if constexpr (STG) { gld16(ap0, sb); gld16(ap1, sb + 4096); }
  __builtin_amdgcn_s_setprio(1);
#pragma unroll
  for (int i = 0; i < 4; ++i)
#pragma unroll
    for (int j = 0; j < 2; ++j) {
      accg[i][j] = __builtin_amdgcn_mfma_f32_16x16x32_bf16(a[i], bg[j], accg[i][j], 0, 0, 0);
      accu[i][j] = __builtin_amdgcn_mfma_f32_16x16x32_bf16(a[i], bu[j], accu[i][j], 0, 0, 0);
    }
  __builtin_amdgcn_s_setprio(0);
  bf16x8 a2[4];
#pragma unroll
  for (int i = 0; i < 4; ++i) a2[i] = *(const bf16x8*)(S + ab0 + (i + 4) * 512);
  if constexpr (STG) {
    gld16(bgp, sb + 8192); gld16(bup, sb + 12288);
    ap0 += 32; ap1 += 32; bgp += 32; bup += 32;
  }
  __builtin_amdgcn_s_setprio(1);
#pragma unroll
  for (int i = 0; i < 4; ++i)
#pragma unroll
    for (int j = 0; j < 2; ++j) {
      accg[i + 4][j] = __builtin_amdgcn_mfma_f32_16x16x32_bf16(a2[i], bg[j], accg[i + 4][j], 0, 0, 0);
      accu[i + 4][j] = __builtin_amdgcn_mfma_f32_16x16x32_bf16(a2[i], bu[j], accu[i + 4][j], 0, 0, 0);
    }
  __builtin_amdgcn_s_setprio(0);
}

// ---- Kernel 3: GEMM1 + fused SiLU-gate. Block 256 M x 128 i-cols, 8 waves. ----
__global__ void __launch_bounds__(512) gemm1_silu(const unsigned short* __restrict__ xb,
                                                  const unsigned short* __restrict__ w1t,
                                                  unsigned short* __restrict__ inter) {
  __shared__ unsigned short SM[65536];   // 128 KiB: 4 slots x (A 8192 | B 8192) elems
  const int e = blockIdx.z;
  const int m0 = blockIdx.x * 256;
  const int c0 = blockIdx.y * 128;       // i-tile
  const int t = threadIdx.x;
  const int lane = t & 63;
  const int wave = t >> 6;
  const int wm = wave >> 2;              // 0..1 : 128-row half
  const int wn = wave & 3;               // 0..3 : 32-col quarter

  const unsigned short* xe = xb + (size_t)e * ME * KD;
  const unsigned short* we = w1t + (size_t)e * 4096 * KD;

  // staging: thread t -> row t/4, 16B chunk (t%4), inverse-swizzled source col
  const int srow = t >> 2;
  const int scol = ((t & 3) * 8) ^ ((t & 32) ? 16 : 0);
  const unsigned short* ap0 = xe + (size_t)(m0 + srow) * KD + scol;          // A rows 0..127
  const unsigned short* ap1 = ap0 + (size_t)128 * KD;                        // A rows 128..255
  const unsigned short* bgp = we + (size_t)(c0 + srow) * KD + scol;          // gate cols
  const unsigned short* bup = bgp + (size_t)2048 * KD;                       // up cols

  // ds_read bases (elements within slot), swizzled
  const int l15 = lane & 15;
  const int kqs = ((lane >> 4) * 8) ^ ((lane & 8) ? 16 : 0);
  const int ab0 = (wm * 128 + l15) * 32 + kqs;
  const int bb0 = 8192 + (wn * 32 + l15) * 32 + kqs;   // gate rows; up = +4096

  f32x4 accg[8][2] = {};
  f32x4 accu[8][2] = {};

  // prologue: stage tiles 0..2 into slots 0..2 (12 loads in flight)
#pragma unroll
  for (int s = 0; s < 3; ++s) {
    unsigned short* sb = SM + s * 16384 + t * 8;
    gld16(ap0, sb); gld16(ap1, sb + 4096); gld16(bgp, sb + 8192); gld16(bup, sb + 12288);
    ap0 += 32; ap1 += 32; bgp += 32; bup += 32;
  }

#pragma unroll 1
  for (int kt = 0; kt < NT - 3; ++kt)    // kt=0..60, stages tile kt+3
    g1_tile<8, true>(SM + (kt & 3) * 16384, ab0, bb0, ap0, ap1, bgp, bup,
                     SM + ((kt + 3) & 3) * 16384 + t * 8, accg, accu);
  g1_tile<8, false>(SM + ((NT - 3) & 3) * 16384, ab0, bb0, ap0, ap1, bgp, bup, SM, accg, accu);
  g1_tile<4, false>(SM + ((NT - 2) & 3) * 16384, ab0, bb0, ap0, ap1, bgp, bup, SM, accg, accu);
  g1_tile<0, false>(SM + ((NT - 1) & 3) * 16384, ab0, bb0, ap0, ap1, bgp, bup, SM, accg, accu);

  // Epilogue: silu(g)*u -> bf16 out-tile in LDS (stride 136), coalesced stores.
  // Out-tile uses SM[0..34816) — disjoint from slot 3 (>=49152) still being read.
  const int quad = lane >> 4;
#pragma unroll
  for (int i = 0; i < 8; ++i)
#pragma unroll
    for (int j = 0; j < 2; ++j)
#pragma unroll
      for (int r = 0; r < 4; ++r) {
        int row = wm * 128 + i * 16 + quad * 4 + r;
        int col = wn * 32 + j * 16 + l15;
        float g = accg[i][j][r];
        float u = accu[i][j][r];
        float sv = g / (1.0f + __expf(-g));
        SM[row * 136 + col] = f2bf(sv * u);
      }
  __syncthreads();
  unsigned short* ip = inter + ((size_t)e * ME + m0) * IDIM + c0;
#pragma unroll
  for (int p = 0; p < 8; ++p) {
    int idx = p * 512 + t;               // 4096 uint4s: 256 rows x 16 parts
    int row = idx >> 4, part = idx & 15;
    *(uint4*)(ip + (size_t)row * IDIM + part * 8) = *(const uint4*)(SM + row * 136 + part * 8);
  }
}

// ---- Kernel 4 tile body: GEMM2 (256x256 tile) ----
template<int VMN, bool STG>
__device__ __forceinline__ void g2_tile(const unsigned short* S, int ab0, int bb0,
                                        const unsigned short*& ap0, const unsigned short*& ap1,
                                        const unsigned short*& bp0, const unsigned short*& bp1,
                                        unsigned short* sb, f32x4 (&acc)[8][4]) {
  wait_vmcnt<VMN>();
  __builtin_amdgcn_s_barrier();
  asm volatile("" ::: "memory");
  bf16x8 a[4], b[4];
#pragma unroll
  for (int i = 0; i < 4; ++i) a[i] = *(const bf16x8*)(S + ab0 + i * 512);
#pragma unroll
  for (int j = 0; j < 4; ++j) b[j] = *(const bf16x8*)(S + bb0 + j * 512);
  if constexpr (STG) { gld16(ap0, sb); gld16(ap1, sb + 4096); }
  __builtin_amdgcn_s_setprio(1);
#pragma unroll
  for (int i = 0; i < 4; ++i)
#pragma unroll
    for (int j = 0; j < 4; ++j)
      acc[i][j] = __builtin_amdgcn_mfma_f32_16x16x32_bf16(a[i], b[j], acc[i][j], 0, 0, 0);
  __builtin_amdgcn_s_setprio(0);
  bf16x8 a2[4];
#pragma unroll
  for (int i = 0; i < 4; ++i) a2[i] = *(const bf16x8*)(S + ab0 + (i + 4) * 512);
  if constexpr (STG) {
    gld16(bp0, sb + 8192); gld16(bp1, sb + 12288);
    ap0 += 32; ap1 += 32; bp0 += 32; bp1 += 32;
  }
  __builtin_amdgcn_s_setprio(1);
#pragma unroll
  for (int i = 0; i < 4; ++i)
#pragma unroll
    for (int j = 0; j < 4; ++j)
      acc[i + 4][j] = __builtin_amdgcn_mfma_f32_16x16x32_bf16(a2[i], b[j], acc[i + 4][j], 0, 0, 0);
  __builtin_amdgcn_s_setprio(0);
}

// ---- Kernel 4: GEMM2, 256x256 block, scattered fp32 output rows ----
__global__ void __launch_bounds__(512) gemm2(const unsigned short* __restrict__ inter,
                                             const unsigned short* __restrict__ w2t,
                                             float* __restrict__ out) {
  __shared__ unsigned short SM[65536];
  const int e = blockIdx.z;
  const int m0 = blockIdx.x * 256;
  const int n0 = blockIdx.y * 256;
  const int t = threadIdx.x;
  const int lane = t & 63;
  const int wave = t >> 6;
  const int wm = wave >> 2;              // 0..1
  const int wn = wave & 3;               // 0..3 : 64-col quarter

  const unsigned short* ae = inter + (size_t)e * ME * IDIM;
  const unsigned short* be = w2t + (size_t)e * HDIM * IDIM;

  const int srow = t >> 2;
  const int scol = ((t & 3) * 8) ^ ((t & 32) ? 16 : 0);
  const unsigned short* ap0 = ae + (size_t)(m0 + srow) * IDIM + scol;
  const unsigned short* ap1 = ap0 + (size_t)128 * IDIM;
  const unsigned short* bp0 = be + (size_t)(n0 + srow) * IDIM + scol;
  const unsigned short* bp1 = bp0 + (size_t)128 * IDIM;

  const int l15 = lane & 15;
  const int kqs = ((lane >> 4) * 8) ^ ((lane & 8) ? 16 : 0);
  const int ab0 = (wm * 128 + l15) * 32 + kqs;
  const int bb0 = 8192 + (wn * 64 + l15) * 32 + kqs;

  f32x4 acc[8][4] = {};

#pragma unroll
  for (int s = 0; s < 3; ++s) {
    unsigned short* sb = SM + s * 16384 + t * 8;
    gld16(ap0, sb); gld16(ap1, sb + 4096); gld16(bp0, sb + 8192); gld16(bp1, sb + 12288);
    ap0 += 32; ap1 += 32; bp0 += 32; bp1 += 32;
  }

#pragma unroll 1
  for (int kt = 0; kt < NT - 3; ++kt)
    g2_tile<8, true>(SM + (kt & 3) * 16384, ab0, bb0, ap0, ap1, bp0, bp1,
                     SM + ((kt + 3) & 3) * 16384 + t * 8, acc);
  g2_tile<8, false>(SM + ((NT - 3) & 3) * 16384, ab0, bb0, ap0, ap1, bp0, bp1, SM, acc);
  g2_tile<4, false>(SM + ((NT - 2) & 3) * 16384, ab0, bb0, ap0, ap1, bp0, bp1, SM, acc);
  g2_tile<0, false>(SM + ((NT - 1) & 3) * 16384, ab0, bb0, ap0, ap1, bp0, bp1, SM, acc);

  // scatter rows: expert-grouped row t -> out row b*2048 + g*4 + e
  const int quad = lane >> 4;
#pragma unroll
  for (int i = 0; i < 8; ++i)
#pragma unroll
    for (int r = 0; r < 4; ++r) {
      int trow = m0 + wm * 128 + i * 16 + quad * 4 + r;
      int b_ = trow >> 9, g_ = trow & 511;
      float* orow = out + ((size_t)((b_ << 11) + (g_ << 2) + e)) * HDIM + n0 + wn * 64;
#pragma unroll
      for (int j = 0; j < 4; ++j) orow[j * 16 + l15] = acc[i][j][r];
    }
}

extern "C" void kernel_launch(void* const* d_in, const int* in_sizes, int n_in,
                              void* d_out, int out_size, void* d_ws, size_t ws_size,
                              hipStream_t stream) {
  (void)in_sizes; (void)n_in; (void)out_size; (void)ws_size;
  const float* x  = (const float*)d_in[0];
  const float* w1 = (const float*)d_in[1];
  const float* w2 = (const float*)d_in[2];
  float* out = (float*)d_out;

  char* ws = (char*)d_ws;
  unsigned short* xb    = (unsigned short*)(ws);
  unsigned short* w1t   = (unsigned short*)(ws + 67108864);
  unsigned short* w2t   = (unsigned short*)(ws + 134217728);
  unsigned short* inter = (unsigned short*)(ws + 167772160);

  pack_x<<<16384, 256, 0, stream>>>(x, xb);
  transpose_cvt<<<dim3(32, 64, 4), 256, 0, stream>>>(w1, w1t, 2048, 4096);
  transpose_cvt<<<dim3(16, 64, 4), 256, 0, stream>>>(w2, w2t, 2048, 2048);
  gemm1_silu<<<dim3(16, 16, 4), 512, 0, stream>>>(xb, w1t, inter);
  gemm2<<<dim3(16, 8, 4), 512, 0, stream>>>(inter, w2t, out);
}

// Round 6
// 718.332 us; speedup vs baseline: 1.0518x; 1.0007x over previous
//
#include <hip/hip_runtime.h>

// Problem constants (B=8, N=2048, H=2048, E=4, I=2048)
#define HDIM 2048
#define IDIM 2048
#define KD   2048
#define ME   4096   // tokens per expert (B*N/E)
#define NT   64     // K tiles of 32

// Workspace layout (requires >= 234,881,024 bytes):
//   xb    @ 0         : bf16 x regrouped [e][t][h], 64 MiB
//   w1t   @ 64 MiB    : bf16 gate_up^T  [e][d][h], 64 MiB
//   w2t   @ 128 MiB   : bf16 down^T     [e][h][i], 32 MiB
//   inter @ 160 MiB   : bf16 silu(g)*u  [e][t][i], 64 MiB

typedef __bf16 bf16x8 __attribute__((ext_vector_type(8)));
typedef float f32x4 __attribute__((ext_vector_type(4)));

__device__ __forceinline__ unsigned short f2bf(float f) {
  unsigned u = __builtin_bit_cast(unsigned, f);
  u += 0x7FFFu + ((u >> 16) & 1u);   // round-to-nearest-even
  return (unsigned short)(u >> 16);
}

__device__ __forceinline__ void gld16(const void* g, void* l) {
  __builtin_amdgcn_global_load_lds(
      (const __attribute__((address_space(1))) unsigned int*)g,
      (__attribute__((address_space(3))) unsigned int*)l, 16, 0, 0);
}

template<int N> __device__ __forceinline__ void wait_vmcnt() {
  asm volatile("s_waitcnt vmcnt(%0)" :: "i"(N) : "memory");
}

// ---- Kernel 1: convert x fp32 -> bf16, regroup rows per expert ----
__global__ void __launch_bounds__(256) pack_x(const float* __restrict__ x,
                                              unsigned short* __restrict__ xb) {
  const int row = blockIdx.x;            // 0..16383 = b*2048 + n
  const int n = row & 2047;
  const int b = row >> 11;
  const int e = n & 3, g = n >> 2;
  const float4* src = (const float4*)(x + (size_t)row * HDIM);
  unsigned short* dst = xb + ((size_t)e * ME + b * 512 + g) * HDIM;
  const int t = threadIdx.x;
  float4 v0 = src[2 * t];
  float4 v1 = src[2 * t + 1];
  uint4 pk;
  pk.x = (unsigned)f2bf(v0.x) | ((unsigned)f2bf(v0.y) << 16);
  pk.y = (unsigned)f2bf(v0.z) | ((unsigned)f2bf(v0.w) << 16);
  pk.z = (unsigned)f2bf(v1.x) | ((unsigned)f2bf(v1.y) << 16);
  pk.w = (unsigned)f2bf(v1.z) | ((unsigned)f2bf(v1.w) << 16);
  *(uint4*)(dst + 8 * t) = pk;
}

// ---- Kernel 2 (v3): transpose + cast fp32 (R x C) -> bf16 (C x R), per expert z ----
// 128x128 tile, 256 threads. The R5-v2 failure: 64-B write segments (4-lane
// groups) on 4-KiB-strided rows ran HBM writes at <1 TB/s. v3 writes 256-B
// segments: 16 lanes x uint4 cover one full output row chunk; loads float4
// (512-B segments). LDS 32 KiB with XOR swizzle on 8-B groups:
//   elem (r,c) -> T[r*128 + (((c>>2) ^ ((r>>3)&15))<<2) + (c&3)]
// write pass: uint2 (4 bf16) at group c4, banks 2g' spread over all 32 (2-way).
// read pass: k-th of 8 gathers at bank 2*((cc>>2)^part)+((cc&3)>>1) -> 32 banks.
__global__ void __launch_bounds__(256) transpose_cvt(const float* __restrict__ src,
                                                     unsigned short* __restrict__ dst,
                                                     int R, int C) {
  __shared__ unsigned short T[16384];
  const size_t eo = (size_t)blockIdx.z * R * C;
  src += eo;
  dst += eo;
  const int c0 = blockIdx.x * 128, r0 = blockIdx.y * 128;
  const int t = threadIdx.x;
#pragma unroll
  for (int p = 0; p < 16; ++p) {
    int idx = p * 256 + t;
    int rr = idx >> 5;          // 0..127 src row
    int c4 = idx & 31;          // float4 index within row (col group of 4)
    float4 v = *(const float4*)(src + (size_t)(r0 + rr) * C + c0 + c4 * 4);
    uint2 pk;
    pk.x = (unsigned)f2bf(v.x) | ((unsigned)f2bf(v.y) << 16);
    pk.y = (unsigned)f2bf(v.z) | ((unsigned)f2bf(v.w) << 16);
    int g = c4 ^ ((rr >> 3) & 15);
    *(uint2*)(T + rr * 128 + g * 4) = pk;
  }
  __syncthreads();
#pragma unroll
  for (int q = 0; q < 8; ++q) {
    int idx = q * 256 + t;
    int cc = idx >> 4;          // 0..127 : output row (source col)
    int part = idx & 15;        // 8-src-row chunk within 128 outputs
    const int gsw = ((cc >> 2) ^ part) * 4 + (cc & 3);
    unsigned short s[8];
#pragma unroll
    for (int k = 0; k < 8; ++k) s[k] = T[(part * 8 + k) * 128 + gsw];
    uint4 w;
    w.x = (unsigned)s[0] | ((unsigned)s[1] << 16);
    w.y = (unsigned)s[2] | ((unsigned)s[3] << 16);
    w.z = (unsigned)s[4] | ((unsigned)s[5] << 16);
    w.w = (unsigned)s[6] | ((unsigned)s[7] << 16);
    *(uint4*)(dst + (size_t)(c0 + cc) * R + r0 + part * 8) = w;
  }
}

// ==== Counted-vmcnt 4-slot pipeline GEMMs (R1 structure, best measured) ====
// LDS: 4 slots x 32 KiB (A[256x32] @ +0, B[256x32] @ +16 KiB), st_16x32 swizzle:
//   element (row, c) lives at byte row*64 + (c ^ ((row&8)?16:0))*2  (linear gld16
//   dest, inverse-swizzled GLOBAL source, swizzled ds_read addr — m201/m173).
// Tile t in slot t&3. Tile t's body stages tile t+3 (slot of t-1: fully read,
// certified by tile t's top barrier). One s_waitcnt vmcnt(8) + one s_barrier per
// tile; vmcnt drains 8->4->0 over the last 3 tiles. 4 gld16/thread/tile.

// ---- Kernel 3 tile body: GEMM1 (A 256xK, gate 128 + up 128 cols per block) ----
template<int VMN, bool STG>
__device__ __forceinline__ void g1_tile(const unsigned short* S, int ab0, int bb0,
                                        const unsigned short*& ap0, const unsigned short*& ap1,
                                        const unsigned short*& bgp, const unsigned short*& bup,
                                        unsigned short* sb,
                                        f32x4 (&accg)[8][2], f32x4 (&accu)[8][2]) {
  wait_vmcnt<VMN>();                 // my stage-loads for this tile landed
  __builtin_amdgcn_s_barrier();      // everyone's landed; prev-tile reads done
  asm volatile("" ::: "memory");
  bf16x8 a[4], bg[2], bu[2];
#pragma unroll
  for (int i = 0; i < 4; ++i) a[i] = *(const bf16x8*)(S + ab0 + i * 512);
#pragma unroll
  for (int j = 0; j < 2; ++j) {
    bg[j] = *(const bf16x8*)(S + bb0 + j * 512);
    bu[j] = *(const bf16x8*)(S + bb0 + 4096 + j * 512);
  }
  if constexpr (STG) { gld16(ap0, sb); gld16(ap1, sb + 4096); }
  __builtin_amdgcn_s_setprio(1);
#pragma unroll
  for (int i = 0; i < 4; ++i)
#pragma unroll
    for (int j = 0; j < 2; ++j) {
      accg[i][j] = __builtin_amdgcn_mfma_f32_16x16x32_bf16(a[i], bg[j], accg[i][j], 0, 0, 0);
      accu[i][j] = __builtin_amdgcn_mfma_f32_16x16x32_bf16(a[i], bu[j], accu[i][j], 0, 0, 0);
    }
  __builtin_amdgcn_s_setprio(0);
  bf16x8 a2[4];
#pragma unroll
  for (int i = 0; i < 4; ++i) a2[i] = *(const bf16x8*)(S + ab0 + (i + 4) * 512);
  if constexpr (STG) {
    gld16(bgp, sb + 8192); gld16(bup, sb + 12288);
    ap0 += 32; ap1 += 32; bgp += 32; bup += 32;
  }
  __builtin_amdgcn_s_setprio(1);
#pragma unroll
  for (int i = 0; i < 4; ++i)
#pragma unroll
    for (int j = 0; j < 2; ++j) {
      accg[i + 4][j] = __builtin_amdgcn_mfma_f32_16x16x32_bf16(a2[i], bg[j], accg[i + 4][j], 0, 0, 0);
      accu[i + 4][j] = __builtin_amdgcn_mfma_f32_16x16x32_bf16(a2[i], bu[j], accu[i + 4][j], 0, 0, 0);
    }
  __builtin_amdgcn_s_setprio(0);
}

// ---- Kernel 3: GEMM1 + fused SiLU-gate. Block 256 M x 128 i-cols, 8 waves. ----
__global__ void __launch_bounds__(512) gemm1_silu(const unsigned short* __restrict__ xb,
                                                  const unsigned short* __restrict__ w1t,
                                                  unsigned short* __restrict__ inter) {
  __shared__ unsigned short SM[65536];   // 128 KiB: 4 slots x (A 8192 | B 8192) elems
  const int e = blockIdx.z;
  const int m0 = blockIdx.x * 256;
  const int c0 = blockIdx.y * 128;       // i-tile
  const int t = threadIdx.x;
  const int lane = t & 63;
  const int wave = t >> 6;
  const int wm = wave >> 2;              // 0..1 : 128-row half
  const int wn = wave & 3;               // 0..3 : 32-col quarter

  const unsigned short* xe = xb + (size_t)e * ME * KD;
  const unsigned short* we = w1t + (size_t)e * 4096 * KD;

  // staging: thread t -> row t/4, 16B chunk (t%4), inverse-swizzled source col
  const int srow = t >> 2;
  const int scol = ((t & 3) * 8) ^ ((t & 32) ? 16 : 0);
  const unsigned short* ap0 = xe + (size_t)(m0 + srow) * KD + scol;          // A rows 0..127
  const unsigned short* ap1 = ap0 + (size_t)128 * KD;                        // A rows 128..255
  const unsigned short* bgp = we + (size_t)(c0 + srow) * KD + scol;          // gate cols
  const unsigned short* bup = bgp + (size_t)2048 * KD;                       // up cols

  // ds_read bases (elements within slot), swizzled
  const int l15 = lane & 15;
  const int kqs = ((lane >> 4) * 8) ^ ((lane & 8) ? 16 : 0);
  const int ab0 = (wm * 128 + l15) * 32 + kqs;
  const int bb0 = 8192 + (wn * 32 + l15) * 32 + kqs;   // gate rows; up = +4096

  f32x4 accg[8][2] = {};
  f32x4 accu[8][2] = {};

  // prologue: stage tiles 0..2 into slots 0..2 (12 loads in flight)
#pragma unroll
  for (int s = 0; s < 3; ++s) {
    unsigned short* sb = SM + s * 16384 + t * 8;
    gld16(ap0, sb); gld16(ap1, sb + 4096); gld16(bgp, sb + 8192); gld16(bup, sb + 12288);
    ap0 += 32; ap1 += 32; bgp += 32; bup += 32;
  }

#pragma unroll 1
  for (int kt = 0; kt < NT - 3; ++kt)    // kt=0..60, stages tile kt+3
    g1_tile<8, true>(SM + (kt & 3) * 16384, ab0, bb0, ap0, ap1, bgp, bup,
                     SM + ((kt + 3) & 3) * 16384 + t * 8, accg, accu);
  g1_tile<8, false>(SM + ((NT - 3) & 3) * 16384, ab0, bb0, ap0, ap1, bgp, bup, SM, accg, accu);
  g1_tile<4, false>(SM + ((NT - 2) & 3) * 16384, ab0, bb0, ap0, ap1, bgp, bup, SM, accg, accu);
  g1_tile<0, false>(SM + ((NT - 1) & 3) * 16384, ab0, bb0, ap0, ap1, bgp, bup, SM, accg, accu);

  // Epilogue: silu(g)*u -> bf16 out-tile in LDS (stride 136), coalesced stores.
  // Out-tile uses SM[0..34816) — disjoint from slot 3 (>=49152) still being read.
  const int quad = lane >> 4;
#pragma unroll
  for (int i = 0; i < 8; ++i)
#pragma unroll
    for (int j = 0; j < 2; ++j)
#pragma unroll
      for (int r = 0; r < 4; ++r) {
        int row = wm * 128 + i * 16 + quad * 4 + r;
        int col = wn * 32 + j * 16 + l15;
        float g = accg[i][j][r];
        float u = accu[i][j][r];
        float sv = g / (1.0f + __expf(-g));
        SM[row * 136 + col] = f2bf(sv * u);
      }
  __syncthreads();
  unsigned short* ip = inter + ((size_t)e * ME + m0) * IDIM + c0;
#pragma unroll
  for (int p = 0; p < 8; ++p) {
    int idx = p * 512 + t;               // 4096 uint4s: 256 rows x 16 parts
    int row = idx >> 4, part = idx & 15;
    *(uint4*)(ip + (size_t)row * IDIM + part * 8) = *(const uint4*)(SM + row * 136 + part * 8);
  }
}

// ---- Kernel 4 tile body: GEMM2 (256x256 tile) ----
template<int VMN, bool STG>
__device__ __forceinline__ void g2_tile(const unsigned short* S, int ab0, int bb0,
                                        const unsigned short*& ap0, const unsigned short*& ap1,
                                        const unsigned short*& bp0, const unsigned short*& bp1,
                                        unsigned short* sb, f32x4 (&acc)[8][4]) {
  wait_vmcnt<VMN>();
  __builtin_amdgcn_s_barrier();
  asm volatile("" ::: "memory");
  bf16x8 a[4], b[4];
#pragma unroll
  for (int i = 0; i < 4; ++i) a[i] = *(const bf16x8*)(S + ab0 + i * 512);
#pragma unroll
  for (int j = 0; j < 4; ++j) b[j] = *(const bf16x8*)(S + bb0 + j * 512);
  if constexpr (STG) { gld16(ap0, sb); gld16(ap1, sb + 4096); }
  __builtin_amdgcn_s_setprio(1);
#pragma unroll
  for (int i = 0; i < 4; ++i)
#pragma unroll
    for (int j = 0; j < 4; ++j)
      acc[i][j] = __builtin_amdgcn_mfma_f32_16x16x32_bf16(a[i], b[j], acc[i][j], 0, 0, 0);
  __builtin_amdgcn_s_setprio(0);
  bf16x8 a2[4];
#pragma unroll
  for (int i = 0; i < 4; ++i) a2[i] = *(const bf16x8*)(S + ab0 + (i + 4) * 512);
  if constexpr (STG) {
    gld16(bp0, sb + 8192); gld16(bp1, sb + 12288);
    ap0 += 32; ap1 += 32; bp0 += 32; bp1 += 32;
  }
  __builtin_amdgcn_s_setprio(1);
#pragma unroll
  for (int i = 0; i < 4; ++i)
#pragma unroll
    for (int j = 0; j < 4; ++j)
      acc[i + 4][j] = __builtin_amdgcn_mfma_f32_16x16x32_bf16(a2[i], b[j], acc[i + 4][j], 0, 0, 0);
  __builtin_amdgcn_s_setprio(0);
}

// ---- Kernel 4: GEMM2, 256x256 block, LDS-staged coalesced fp32 output ----
__global__ void __launch_bounds__(512) gemm2(const unsigned short* __restrict__ inter,
                                             const unsigned short* __restrict__ w2t,
                                             float* __restrict__ out) {
  __shared__ unsigned short SM[65536];
  const int e = blockIdx.z;
  const int m0 = blockIdx.x * 256;
  const int n0 = blockIdx.y * 256;
  const int t = threadIdx.x;
  const int lane = t & 63;
  const int wave = t >> 6;
  const int wm = wave >> 2;              // 0..1
  const int wn = wave & 3;               // 0..3 : 64-col quarter

  const unsigned short* ae = inter + (size_t)e * ME * IDIM;
  const unsigned short* be = w2t + (size_t)e * HDIM * IDIM;

  const int srow = t >> 2;
  const int scol = ((t & 3) * 8) ^ ((t & 32) ? 16 : 0);
  const unsigned short* ap0 = ae + (size_t)(m0 + srow) * IDIM + scol;
  const unsigned short* ap1 = ap0 + (size_t)128 * IDIM;
  const unsigned short* bp0 = be + (size_t)(n0 + srow) * IDIM + scol;
  const unsigned short* bp1 = bp0 + (size_t)128 * IDIM;

  const int l15 = lane & 15;
  const int kqs = ((lane >> 4) * 8) ^ ((lane & 8) ? 16 : 0);
  const int ab0 = (wm * 128 + l15) * 32 + kqs;
  const int bb0 = 8192 + (wn * 64 + l15) * 32 + kqs;

  f32x4 acc[8][4] = {};

#pragma unroll
  for (int s = 0; s < 3; ++s) {
    unsigned short* sb = SM + s * 16384 + t * 8;
    gld16(ap0, sb); gld16(ap1, sb + 4096); gld16(bp0, sb + 8192); gld16(bp1, sb + 12288);
    ap0 += 32; ap1 += 32; bp0 += 32; bp1 += 32;
  }

#pragma unroll 1
  for (int kt = 0; kt < NT - 3; ++kt)
    g2_tile<8, true>(SM + (kt & 3) * 16384, ab0, bb0, ap0, ap1, bp0, bp1,
                     SM + ((kt + 3) & 3) * 16384 + t * 8, acc);
  g2_tile<8, false>(SM + ((NT - 3) & 3) * 16384, ab0, bb0, ap0, ap1, bp0, bp1, SM, acc);
  g2_tile<4, false>(SM + ((NT - 2) & 3) * 16384, ab0, bb0, ap0, ap1, bp0, bp1, SM, acc);
  g2_tile<0, false>(SM + ((NT - 1) & 3) * 16384, ab0, bb0, ap0, ap1, bp0, bp1, SM, acc);

  // Epilogue: stage 64-row fp32 chunks in LDS, store 1-KiB coalesced segments.
  // Lf covers bytes [0, 66560) — disjoint from slot 3 [98304, 131072), the only
  // region still being ds_read after the last tile's top barrier.
  float* Lf = (float*)SM;                // [64][260] fp32
  const int quad = lane >> 4;
#pragma unroll
  for (int c = 0; c < 4; ++c) {
    if (wm == (c >> 1)) {
      const int ibase = (c & 1) * 4;
#pragma unroll
      for (int ii = 0; ii < 4; ++ii)
#pragma unroll
        for (int j = 0; j < 4; ++j)
#pragma unroll
          for (int r = 0; r < 4; ++r) {
            int rloc = ii * 16 + quad * 4 + r;
            Lf[rloc * 260 + wn * 64 + j * 16 + l15] = acc[ibase + ii][j][r];
          }
    }
    __syncthreads();
#pragma unroll
    for (int p = 0; p < 8; ++p) {
      int idx = p * 512 + t;
      int rloc = idx >> 6, part = idx & 63;    // 64 rows x 64 float4
      int trow = m0 + c * 64 + rloc;
      int b_ = trow >> 9, g_ = trow & 511;
      float* orow = out + ((size_t)((b_ << 11) + (g_ << 2) + e)) * HDIM + n0;
      *(float4*)(orow + part * 4) = *(const float4*)(Lf + rloc * 260 + part * 4);
    }
    __syncthreads();
  }
}

extern "C" void kernel_launch(void* const* d_in, const int* in_sizes, int n_in,
                              void* d_out, int out_size, void* d_ws, size_t ws_size,
                              hipStream_t stream) {
  (void)in_sizes; (void)n_in; (void)out_size; (void)ws_size;
  const float* x  = (const float*)d_in[0];
  const float* w1 = (const float*)d_in[1];
  const float* w2 = (const float*)d_in[2];
  float* out = (float*)d_out;

  char* ws = (char*)d_ws;
  unsigned short* xb    = (unsigned short*)(ws);
  unsigned short* w1t   = (unsigned short*)(ws + 67108864);
  unsigned short* w2t   = (unsigned short*)(ws + 134217728);
  unsigned short* inter = (unsigned short*)(ws + 167772160);

  pack_x<<<16384, 256, 0, stream>>>(x, xb);
  transpose_cvt<<<dim3(32, 16, 4), 256, 0, stream>>>(w1, w1t, 2048, 4096);
  transpose_cvt<<<dim3(16, 16, 4), 256, 0, stream>>>(w2, w2t, 2048, 2048);
  gemm1_silu<<<dim3(16, 16, 4), 512, 0, stream>>>(xb, w1t, inter);
  gemm2<<<dim3(16, 8, 4), 512, 0, stream>>>(inter, w2t, out);
}